// Round 7
// baseline (273.314 us; speedup 1.0000x reference)
//
#include <hip/hip_runtime.h>

#define NUM_NODES 20000
#define NUM_EDGES 640000
#define DIM 128
#define NUM_HEADS 8
#define HEAD_DIM 16
#define NEG_SLOPE 0.01f

typedef __attribute__((ext_vector_type(4))) float float4v;

#define TOTAL (NUM_EDGES * NUM_HEADS)  // 5,120,000
#define HALF (TOTAL / 2)               // 2,560,000 (divisible by 8)

// edge_index may be int32 (harness contract) or int64 (reference dtype).
// int64 little-endian with values < 2^31 => every odd 32-bit word is zero.
// flag != 0  =>  int32 layout.
__global__ void k_detect(const unsigned* __restrict__ ei_raw, int* __restrict__ flag) {
    if (ei_raw[2 * threadIdx.x + 1] != 0) atomicOr(flag, 1);
}

__device__ __forceinline__ int get_target(const int* __restrict__ ei, int e, int is32) {
    return is32 ? ei[NUM_EDGES + e] : ei[2 * (NUM_EDGES + e)];
}

// K1: two independent (edge,head) chains per thread. launch_bounds(256,4)
// gives the register allocator a 128-VGPR budget so all 16 float4 loads can
// be in flight at once (round 5: plain launch_bounds(256) -> 48 VGPR ->
// ~4-outstanding serialized loads, 1.5 TB/s read rate).
// No max-shift: |score| <~ 35, exp safe in f32, softmax ratio unchanged.
__global__ __launch_bounds__(256, 4) void k_main(
    const int* __restrict__ ei,
    const float* __restrict__ msg,         // (E,128) f32
    const float* __restrict__ xe,          // (N,128) f32
    const float* __restrict__ wt,          // (8,32) f32
    float* __restrict__ out_msg,           // (E,128) f32
    float* __restrict__ ex_ws,             // (E,8) f32 ws: exp(score)
    float* __restrict__ seg_sum,           // (N,8) f32 ws, pre-zeroed
    const int* __restrict__ flag)
{
    // Transposed weights: w[j*8+h] = wt[h*32+j] -> 8-lane groups with equal j
    // hit 8 consecutive banks, same-address broadcast within each group.
    __shared__ float w[NUM_HEADS * 2 * HEAD_DIM];
    const int tid = threadIdx.x;
    {
        const int h = tid >> 5, j = tid & 31;
        w[j * 8 + h] = wt[tid];
    }
    __syncthreads();

    const int is32 = *flag;
    const int gid0 = blockIdx.x * 256 + tid;
    const int gid1 = gid0 + HALF;

    const int h = gid0 & 7;          // same for both chains (HALF % 8 == 0)
    const int hh = h * HEAD_DIM;
    const int e0 = gid0 >> 3;
    const int e1 = gid1 >> 3;

    const int t0 = get_target(ei, e0, is32);
    const int t1 = get_target(ei, e1, is32);

    const float* mp0 = msg + (size_t)e0 * DIM + hh;
    const float* mp1 = msg + (size_t)e1 * DIM + hh;
    const float* xp0 = xe + (size_t)t0 * DIM + hh;
    const float* xp1 = xe + (size_t)t1 * DIM + hh;

    // Issue ALL 16 loads before any use.
    float4v m0[4], m1[4], x0[4], x1[4];
#pragma unroll
    for (int i = 0; i < 4; i++) m0[i] = *(const float4v*)(mp0 + 4 * i);
#pragma unroll
    for (int i = 0; i < 4; i++) m1[i] = *(const float4v*)(mp1 + 4 * i);
#pragma unroll
    for (int i = 0; i < 4; i++) x0[i] = *(const float4v*)(xp0 + 4 * i);
#pragma unroll
    for (int i = 0; i < 4; i++) x1[i] = *(const float4v*)(xp1 + 4 * i);

    // Bit-exact fused copies (regular stores: L2 merges 16B fragments).
    float* op0 = out_msg + (size_t)e0 * DIM + hh;
    float* op1 = out_msg + (size_t)e1 * DIM + hh;
#pragma unroll
    for (int i = 0; i < 4; i++) *(float4v*)(op0 + 4 * i) = m0[i];
#pragma unroll
    for (int i = 0; i < 4; i++) *(float4v*)(op1 + 4 * i) = m1[i];

    float s0 = 0.f, s1 = 0.f;
#pragma unroll
    for (int i = 0; i < 4; i++)
#pragma unroll
        for (int j = 0; j < 4; j++) {
            const float wm = w[(i * 4 + j) * 8 + h];
            const float wx = w[(16 + i * 4 + j) * 8 + h];
            s0 += m0[i][j] * wm;
            s0 += x0[i][j] * wx;
            s1 += m1[i][j] * wm;
            s1 += x1[i][j] * wx;
        }

    s0 = (s0 >= 0.f) ? s0 : NEG_SLOPE * s0;  // LeakyReLU
    s1 = (s1 >= 0.f) ? s1 : NEG_SLOPE * s1;

    const float ex0 = __expf(s0);
    const float ex1 = __expf(s1);

    ex_ws[gid0] = ex0;
    ex_ws[gid1] = ex1;
    atomicAdd(&seg_sum[t0 * NUM_HEADS + h], ex0);
    atomicAdd(&seg_sum[t1 * NUM_HEADS + h], ex1);
}

// K2: alpha = ex / seg_sum[key].
__global__ __launch_bounds__(256) void k_norm(
    const int* __restrict__ ei,
    const float* __restrict__ ex_ws,
    const float* __restrict__ seg_sum,
    float* __restrict__ out_alpha,
    const int* __restrict__ flag)
{
    const int gid = blockIdx.x * 256 + threadIdx.x;
    const int h = gid & 7;
    const int e = gid >> 3;

    const int t = get_target(ei, e, *flag);
    out_alpha[gid] = ex_ws[gid] / (seg_sum[t * NUM_HEADS + h] + 1e-16f);
}

extern "C" void kernel_launch(void* const* d_in, const int* in_sizes, int n_in,
                              void* d_out, int out_size, void* d_ws, size_t ws_size,
                              hipStream_t stream) {
    const int* ei = (const int*)d_in[0];
    const float* msg = (const float*)d_in[1];
    const float* xe = (const float*)d_in[2];
    const float* wt = (const float*)d_in[3];

    float* out_msg = (float*)d_out;                            // (E,128) f32
    float* out_alpha = out_msg + (size_t)NUM_EDGES * DIM;      // (E,8) f32

    char* ws = (char*)d_ws;
    float* ex_ws = (float*)ws;                                 // E*8 f32 = 20.48 MB
    size_t off = (size_t)TOTAL * sizeof(float);
    float* seg_sum = (float*)(ws + off);                       // N*8 f32
    int* flag = (int*)(ws + off + (size_t)NUM_NODES * NUM_HEADS * 4);

    // Zero seg_sum and flag in one memset.
    hipMemsetAsync(seg_sum, 0, (size_t)NUM_NODES * NUM_HEADS * 4 + 4, stream);

    k_detect<<<1, 256, 0, stream>>>((const unsigned*)ei, flag);
    k_main<<<HALF / 256, 256, 0, stream>>>(ei, msg, xe, wt, out_msg, ex_ws,
                                           seg_sum, flag);
    k_norm<<<TOTAL / 256, 256, 0, stream>>>(ei, ex_ws, seg_sum, out_alpha, flag);
}

// Round 8
// 186.302 us; speedup vs baseline: 1.4670x; 1.4670x over previous
//
#include <hip/hip_runtime.h>

#define NUM_NODES 20000
#define NUM_EDGES 640000
#define DIM 128
#define NUM_HEADS 8
#define HEAD_DIM 16
#define NEG_SLOPE 0.01f

typedef __attribute__((ext_vector_type(4))) float float4v;

#define TOTAL (NUM_EDGES * NUM_HEADS)  // 5,120,000
#define NKEYS (NUM_NODES * NUM_HEADS)  // 160,000

// edge_index may be int32 (harness contract) or int64 (reference dtype).
// int64 little-endian with values < 2^31 => every odd 32-bit word is zero.
// flag != 0  =>  int32 layout.
__global__ void k_detect(const unsigned* __restrict__ ei_raw, int* __restrict__ flag) {
    if (ei_raw[2 * threadIdx.x + 1] != 0) atomicOr(flag, 1);
}

__device__ __forceinline__ int get_target(const int* __restrict__ ei, int e, int is32) {
    return is32 ? ei[NUM_EDGES + e] : ei[2 * (NUM_EDGES + e)];
}

// K-proj: proj[t*8+h] = dot(x_e[t, h*16 .. h*16+16], w[h, 16..32]).
// Turns the per-edge 64 B gather from the 10 MB x_e table into a per-edge
// 4 B lookup in a 640 KB table (L2-resident on every XCD).
__global__ __launch_bounds__(256) void k_proj(
    const float* __restrict__ xe,     // (N,128) f32
    const float* __restrict__ wt,     // (8,32) f32
    float* __restrict__ proj)         // (N*8) f32
{
    // Transposed x-half of weights: wx[j*8+h] = wt[h*32+16+j] -> 8-lane
    // groups with equal j hit 8 consecutive banks.
    __shared__ float wx[HEAD_DIM * NUM_HEADS];
    const int tid = threadIdx.x;
    {
        const int h = tid >> 5, j = tid & 31;
        if (j >= 16) wx[(j - 16) * 8 + h] = wt[tid];
    }
    __syncthreads();

    const int gid = blockIdx.x * 256 + tid;  // (t,h); 625*256 == NKEYS exact
    const int h = gid & 7;
    const int t = gid >> 3;

    const float* xp = xe + (size_t)t * DIM + h * HEAD_DIM;
    float4v x[4];
#pragma unroll
    for (int i = 0; i < 4; i++) x[i] = *(const float4v*)(xp + 4 * i);

    float s = 0.f;
#pragma unroll
    for (int i = 0; i < 4; i++)
#pragma unroll
        for (int j = 0; j < 4; j++) s += x[i][j] * wx[(i * 4 + j) * 8 + h];

    proj[gid] = s;
}

// K-main: per (edge,head): stream msg slice (fused bit-exact copy), dot with
// msg-half weights, + proj[target,h] (4 B, L2-hot), LeakyReLU, exp, store ex,
// atomicAdd segment sum. No max-shift: |s| <~ 40 so f32 exp is safe and the
// softmax ratio is identical.
__global__ __launch_bounds__(256) void k_main(
    const int* __restrict__ ei,
    const float* __restrict__ msg,         // (E,128) f32
    const float* __restrict__ wt,          // (8,32) f32
    const float* __restrict__ proj,        // (N*8) f32
    float* __restrict__ out_msg,           // (E,128) f32
    float* __restrict__ ex_ws,             // (E,8) f32 ws
    float* __restrict__ seg_sum,           // (N*8) f32 ws, pre-zeroed
    const int* __restrict__ flag)
{
    // Transposed msg-half of weights: wm[j*8+h] = wt[h*32+j].
    __shared__ float wm[HEAD_DIM * NUM_HEADS];
    const int tid = threadIdx.x;
    {
        const int h = tid >> 5, j = tid & 31;
        if (j < 16) wm[j * 8 + h] = wt[tid];
    }
    __syncthreads();

    const int gid = blockIdx.x * 256 + tid;  // (e,h); 20000*256 == TOTAL exact
    const int h = gid & 7;
    const int e = gid >> 3;

    const int t = get_target(ei, e, *flag);
    const float px = proj[t * NUM_HEADS + h];  // 4 B, L2-resident table

    const float* mp = msg + (size_t)e * DIM + h * HEAD_DIM;
    float4v m[4];
#pragma unroll
    for (int i = 0; i < 4; i++) m[i] = *(const float4v*)(mp + 4 * i);

    // Bit-exact fused copy (64 B/thread, coalesced; wave covers 4 KB).
    float* op = out_msg + (size_t)e * DIM + h * HEAD_DIM;
#pragma unroll
    for (int i = 0; i < 4; i++) *(float4v*)(op + 4 * i) = m[i];

    float s = px;
#pragma unroll
    for (int i = 0; i < 4; i++)
#pragma unroll
        for (int j = 0; j < 4; j++) s += m[i][j] * wm[(i * 4 + j) * 8 + h];

    s = (s >= 0.f) ? s : NEG_SLOPE * s;  // LeakyReLU

    const float ex = __expf(s);
    ex_ws[gid] = ex;
    atomicAdd(&seg_sum[t * NUM_HEADS + h], ex);
}

// K-norm: alpha = ex / seg_sum[key].
__global__ __launch_bounds__(256) void k_norm(
    const int* __restrict__ ei,
    const float* __restrict__ ex_ws,
    const float* __restrict__ seg_sum,
    float* __restrict__ out_alpha,
    const int* __restrict__ flag)
{
    const int gid = blockIdx.x * 256 + threadIdx.x;
    const int h = gid & 7;
    const int e = gid >> 3;

    const int t = get_target(ei, e, *flag);
    out_alpha[gid] = ex_ws[gid] / (seg_sum[t * NUM_HEADS + h] + 1e-16f);
}

extern "C" void kernel_launch(void* const* d_in, const int* in_sizes, int n_in,
                              void* d_out, int out_size, void* d_ws, size_t ws_size,
                              hipStream_t stream) {
    const int* ei = (const int*)d_in[0];
    const float* msg = (const float*)d_in[1];
    const float* xe = (const float*)d_in[2];
    const float* wt = (const float*)d_in[3];

    float* out_msg = (float*)d_out;                            // (E,128) f32
    float* out_alpha = out_msg + (size_t)NUM_EDGES * DIM;      // (E,8) f32

    char* ws = (char*)d_ws;
    float* ex_ws = (float*)ws;                                 // E*8 f32 = 20.48 MB
    size_t off = (size_t)TOTAL * sizeof(float);
    float* proj = (float*)(ws + off);                          // N*8 f32
    float* seg_sum = (float*)(ws + off + (size_t)NKEYS * 4);   // N*8 f32
    int* flag = (int*)(ws + off + (size_t)NKEYS * 8);

    // Zero seg_sum and flag in one memset.
    hipMemsetAsync(seg_sum, 0, (size_t)NKEYS * 4 + 4, stream);

    k_detect<<<1, 256, 0, stream>>>((const unsigned*)ei, flag);
    k_proj<<<NKEYS / 256, 256, 0, stream>>>(xe, wt, proj);
    k_main<<<TOTAL / 256, 256, 0, stream>>>(ei, msg, wt, proj, out_msg, ex_ws,
                                            seg_sum, flag);
    k_norm<<<TOTAL / 256, 256, 0, stream>>>(ei, ex_ws, seg_sum, out_alpha, flag);
}

// Round 9
// 184.151 us; speedup vs baseline: 1.4842x; 1.0117x over previous
//
#include <hip/hip_runtime.h>

#define NUM_NODES 20000
#define NUM_EDGES 640000
#define DIM 128
#define NUM_HEADS 8
#define HEAD_DIM 16
#define NEG_SLOPE 0.01f

typedef __attribute__((ext_vector_type(4))) float float4v;

#define TOTAL (NUM_EDGES * NUM_HEADS)  // 5,120,000
#define HALF (TOTAL / 2)               // 2,560,000 (divisible by 8)
#define NKEYS (NUM_NODES * NUM_HEADS)  // 160,000

__device__ __forceinline__ int get_target(const int* __restrict__ ei, int e, int is32) {
    return is32 ? ei[NUM_EDGES + e] : ei[2 * (NUM_EDGES + e)];
}

// K-proj (also: seg_sum zeroing + edge_index dtype detect, saving 2 dispatches):
//   proj[t*8+h] = dot(x_e[t, h*16..], w[h, 16..32])
// Turns k_main's 64 B gather from the 10 MB x_e table into a 4 B lookup in a
// 640 KB L2-resident table.
__global__ __launch_bounds__(256) void k_proj(
    const float* __restrict__ xe,     // (N,128) f32
    const float* __restrict__ wt,     // (8,32) f32
    const unsigned* __restrict__ ei_raw,
    float* __restrict__ proj,         // (N*8) f32 ws
    float* __restrict__ seg_sum,      // (N*8) f32 ws (zeroed here)
    int* __restrict__ flag)           // ws: 1 => int32 edge_index
{
    __shared__ float wx[HEAD_DIM * NUM_HEADS];
    __shared__ int sflag;
    const int tid = threadIdx.x;
    if (tid == 0) sflag = 0;
    {
        const int h = tid >> 5, j = tid & 31;
        if (j >= 16) wx[(j - 16) * 8 + h] = wt[tid];  // transposed x-half
    }
    __syncthreads();

    // int64 little-endian edge ids < 2^31 => odd 32-bit words all zero.
    if (blockIdx.x == 0) {
        if (ei_raw[2 * tid + 1] != 0) atomicOr(&sflag, 1);
        __syncthreads();
        if (tid == 0) *flag = sflag;
    }

    const int gid = blockIdx.x * 256 + tid;  // 625*256 == NKEYS exact
    seg_sum[gid] = 0.f;

    const int h = gid & 7;
    const int t = gid >> 3;

    const float* xp = xe + (size_t)t * DIM + h * HEAD_DIM;
    float4v x[4];
#pragma unroll
    for (int i = 0; i < 4; i++) x[i] = *(const float4v*)(xp + 4 * i);

    float s = 0.f;
#pragma unroll
    for (int i = 0; i < 4; i++)
#pragma unroll
        for (int j = 0; j < 4; j++) s += x[i][j] * wx[(i * 4 + j) * 8 + h];

    proj[gid] = s;
}

// K-main: two independent (edge,head) stream-chains per thread. Per item:
// fused bit-exact msg copy, dot vs LDS msg-half weights, + proj[t,h] (L2-hot),
// LeakyReLU, exp, store ex, atomicAdd segment sum. No max-shift: |s| <~ 40,
// f32 exp safe, softmax ratio identical.
__global__ __launch_bounds__(256) void k_main(
    const int* __restrict__ ei,
    const float* __restrict__ msg,         // (E,128) f32
    const float* __restrict__ wt,          // (8,32) f32
    const float* __restrict__ proj,        // (N*8) f32
    float* __restrict__ out_msg,           // (E,128) f32
    float* __restrict__ ex_ws,             // (E,8) f32 ws
    float* __restrict__ seg_sum,           // (N*8) f32 ws (zeroed)
    const int* __restrict__ flag)
{
    __shared__ float wm[HEAD_DIM * NUM_HEADS];
    const int tid = threadIdx.x;
    {
        const int h = tid >> 5, j = tid & 31;
        if (j < 16) wm[j * 8 + h] = wt[tid];  // transposed msg-half
    }
    __syncthreads();

    const int is32 = *flag;
    const int gid0 = blockIdx.x * 256 + tid;  // 10000*256 == HALF exact
    const int gid1 = gid0 + HALF;

    const int h = gid0 & 7;  // same for both chains (HALF % 8 == 0)
    const int hh = h * HEAD_DIM;
    const int e0 = gid0 >> 3;
    const int e1 = gid1 >> 3;

    const int t0 = get_target(ei, e0, is32);
    const int t1 = get_target(ei, e1, is32);

    const float* mp0 = msg + (size_t)e0 * DIM + hh;
    const float* mp1 = msg + (size_t)e1 * DIM + hh;

    float4v m0[4], m1[4];
#pragma unroll
    for (int i = 0; i < 4; i++) m0[i] = *(const float4v*)(mp0 + 4 * i);
#pragma unroll
    for (int i = 0; i < 4; i++) m1[i] = *(const float4v*)(mp1 + 4 * i);

    const float px0 = proj[t0 * NUM_HEADS + h];
    const float px1 = proj[t1 * NUM_HEADS + h];

    float* op0 = out_msg + (size_t)e0 * DIM + hh;
    float* op1 = out_msg + (size_t)e1 * DIM + hh;
#pragma unroll
    for (int i = 0; i < 4; i++) *(float4v*)(op0 + 4 * i) = m0[i];
#pragma unroll
    for (int i = 0; i < 4; i++) *(float4v*)(op1 + 4 * i) = m1[i];

    float s0 = px0, s1 = px1;
#pragma unroll
    for (int i = 0; i < 4; i++)
#pragma unroll
        for (int j = 0; j < 4; j++) {
            const float wv = wm[(i * 4 + j) * 8 + h];
            s0 += m0[i][j] * wv;
            s1 += m1[i][j] * wv;
        }

    s0 = (s0 >= 0.f) ? s0 : NEG_SLOPE * s0;
    s1 = (s1 >= 0.f) ? s1 : NEG_SLOPE * s1;

    const float ex0 = __expf(s0);
    const float ex1 = __expf(s1);

    ex_ws[gid0] = ex0;
    ex_ws[gid1] = ex1;
    atomicAdd(&seg_sum[t0 * NUM_HEADS + h], ex0);
    atomicAdd(&seg_sum[t1 * NUM_HEADS + h], ex1);
}

// K-norm: 4 consecutive (e,h) items per thread — all share one edge e
// (4*tid & 7 in {0,4}), so: 1 ei load, float4 ex, float4 seg_sum (consecutive
// keys), float4 alpha store.
__global__ __launch_bounds__(256) void k_norm(
    const int* __restrict__ ei,
    const float* __restrict__ ex_ws,
    const float* __restrict__ seg_sum,
    float* __restrict__ out_alpha,
    const int* __restrict__ flag)
{
    const int base = (blockIdx.x * 256 + threadIdx.x) * 4;  // 5000 blocks exact
    const int h0 = base & 7;                                // 0 or 4
    const int e = base >> 3;

    const int t = get_target(ei, e, *flag);

    const float4v ex = *(const float4v*)(ex_ws + base);
    const float4v den = *(const float4v*)(seg_sum + t * NUM_HEADS + h0);

    float4v a;
#pragma unroll
    for (int j = 0; j < 4; j++) a[j] = ex[j] / (den[j] + 1e-16f);

    *(float4v*)(out_alpha + base) = a;
}

extern "C" void kernel_launch(void* const* d_in, const int* in_sizes, int n_in,
                              void* d_out, int out_size, void* d_ws, size_t ws_size,
                              hipStream_t stream) {
    const int* ei = (const int*)d_in[0];
    const float* msg = (const float*)d_in[1];
    const float* xe = (const float*)d_in[2];
    const float* wt = (const float*)d_in[3];

    float* out_msg = (float*)d_out;                            // (E,128) f32
    float* out_alpha = out_msg + (size_t)NUM_EDGES * DIM;      // (E,8) f32

    char* ws = (char*)d_ws;
    float* ex_ws = (float*)ws;                                 // E*8 f32
    size_t off = (size_t)TOTAL * sizeof(float);
    float* proj = (float*)(ws + off);                          // N*8 f32
    float* seg_sum = (float*)(ws + off + (size_t)NKEYS * 4);   // N*8 f32
    int* flag = (int*)(ws + off + (size_t)NKEYS * 8);

    k_proj<<<NKEYS / 256, 256, 0, stream>>>(xe, wt, (const unsigned*)ei, proj,
                                            seg_sum, flag);
    k_main<<<HALF / 256, 256, 0, stream>>>(ei, msg, wt, proj, out_msg, ex_ws,
                                           seg_sum, flag);
    k_norm<<<TOTAL / 1024, 256, 0, stream>>>(ei, ex_ws, seg_sum, out_alpha, flag);
}

// Round 10
// 139.002 us; speedup vs baseline: 1.9663x; 1.3248x over previous
//
#include <hip/hip_runtime.h>

#define NUM_NODES 20000
#define NUM_EDGES 640000
#define DIM 128
#define NUM_HEADS 8
#define HEAD_DIM 16
#define NEG_SLOPE 0.01f

typedef __attribute__((ext_vector_type(4))) float float4v;

#define TOTAL (NUM_EDGES * NUM_HEADS)  // 5,120,000
#define NKEYS (NUM_NODES * NUM_HEADS)  // 160,000
#define ROUNDS 4

__device__ __forceinline__ int get_target(const int* __restrict__ ei, int e, int is32) {
    return is32 ? ei[NUM_EDGES + e] : ei[2 * (NUM_EDGES + e)];
}

// K-proj (+ seg_sum zeroing + edge_index dtype detect).
// Lane-major: lane i loads float4 i of a 2-node span -> every global load
// instruction covers 1 KB contiguous. 4-lane groups own one (node,head)
// 16-float slice; per-lane private weight float4; shfl_xor reduce.
__global__ __launch_bounds__(256) void k_proj(
    const float* __restrict__ xe,     // (N,128) f32
    const float* __restrict__ wt,     // (8,32) f32
    const unsigned* __restrict__ ei_raw,
    float* __restrict__ proj,         // (N*8) f32 ws
    float* __restrict__ seg_sum,      // (N*8) f32 ws (zeroed here)
    int* __restrict__ flag)           // ws: 1 => int32 edge_index
{
    const int tid = threadIdx.x;

    // dtype detect: int64 little-endian node ids < 2^31 => odd words zero.
    if (blockIdx.x == 0) {
        __shared__ int sflag;
        if (tid == 0) sflag = 0;
        __syncthreads();
        if (ei_raw[2 * tid + 1] != 0) atomicOr(&sflag, 1);
        __syncthreads();
        if (tid == 0) *flag = sflag;
    }

    // seg_sum zeroing: 625 blocks * 256 threads == NKEYS exactly.
    seg_sum[blockIdx.x * 256 + tid] = 0.f;

    const int lane = tid & 63;
    const int wave = tid >> 6;
    const int f = lane & 31;      // float4 index within node row (32 per row)
    const int h = f >> 2;
    const int r = f & 3;
    const int half = lane >> 5;   // which of the 2 nodes per round

    // x-half weight: wt[h, 16 + r*4 ..]
    const float4v wv = *(const float4v*)(wt + h * 32 + 16 + r * 4);

    const int nbase = (blockIdx.x * 4 + wave) * (2 * ROUNDS);  // 32 nodes/block
    const float4v* xe4 = (const float4v*)xe;

    float4v x[ROUNDS];
#pragma unroll
    for (int k = 0; k < ROUNDS; k++)
        x[k] = xe4[(size_t)(nbase + 2 * k) * 32 + lane];

#pragma unroll
    for (int k = 0; k < ROUNDS; k++) {
        float p = x[k][0] * wv[0] + x[k][1] * wv[1] + x[k][2] * wv[2] +
                  x[k][3] * wv[3];
        p += __shfl_xor(p, 1);
        p += __shfl_xor(p, 2);
        if (r == 0) {
            const int n = nbase + 2 * k + half;
            proj[n * NUM_HEADS + h] = p;  // 16 lanes -> 64 B contiguous
        }
    }
}

// K-main, lane-major: every msg load / out store instruction is 1 KB
// contiguous (lane i <-> float4 i of a 2-edge span). 4-lane group owns one
// (edge,head): per-lane partial dot vs private weight float4, shfl_xor
// reduce, + proj[t,h] (L2-hot 640 KB table), LeakyReLU, exp, ex store
// (64 B contiguous across the 16 r==0 lanes), atomicAdd segment sum.
// No max-shift: |s| <~ 40, f32 exp safe, softmax ratio identical.
__global__ __launch_bounds__(256) void k_main(
    const int* __restrict__ ei,
    const float* __restrict__ msg,         // (E,128) f32
    const float* __restrict__ wt,          // (8,32) f32
    const float* __restrict__ proj,        // (N*8) f32
    float* __restrict__ out_msg,           // (E,128) f32
    float* __restrict__ ex_ws,             // (E,8) f32 ws
    float* __restrict__ seg_sum,           // (N*8) f32 ws (zeroed)
    const int* __restrict__ flag)
{
    const int tid = threadIdx.x;
    const int lane = tid & 63;
    const int wave = tid >> 6;
    const int f = lane & 31;
    const int h = f >> 2;
    const int r = f & 3;
    const int half = lane >> 5;

    // msg-half weight: wt[h, r*4 ..]
    const float4v wv = *(const float4v*)(wt + h * 32 + r * 4);

    const int is32 = *flag;
    const int ebase = (blockIdx.x * 4 + wave) * (2 * ROUNDS);  // 32 edges/block
    const float4v* msg4 = (const float4v*)msg;
    float4v* out4 = (float4v*)out_msg;

    // Issue all independent loads up front (12 in flight / thread).
    float4v m[ROUNDS];
#pragma unroll
    for (int k = 0; k < ROUNDS; k++)
        m[k] = msg4[(size_t)(ebase + 2 * k) * 32 + lane];

    int t[ROUNDS];
#pragma unroll
    for (int k = 0; k < ROUNDS; k++)
        t[k] = get_target(ei, ebase + 2 * k + half, is32);

    float px[ROUNDS];
#pragma unroll
    for (int k = 0; k < ROUNDS; k++) px[k] = proj[t[k] * NUM_HEADS + h];

    // Bit-exact fused copy (coalesced 1 KB per instruction).
#pragma unroll
    for (int k = 0; k < ROUNDS; k++)
        out4[(size_t)(ebase + 2 * k) * 32 + lane] = m[k];

#pragma unroll
    for (int k = 0; k < ROUNDS; k++) {
        float p = m[k][0] * wv[0] + m[k][1] * wv[1] + m[k][2] * wv[2] +
                  m[k][3] * wv[3];
        p += __shfl_xor(p, 1);
        p += __shfl_xor(p, 2);
        float s = p + px[k];
        s = (s >= 0.f) ? s : NEG_SLOPE * s;  // LeakyReLU
        const float ex = __expf(s);
        if (r == 0) {
            const int e = ebase + 2 * k + half;
            ex_ws[e * NUM_HEADS + h] = ex;
            atomicAdd(&seg_sum[t[k] * NUM_HEADS + h], ex);
        }
    }
}

// K-norm: 4 consecutive (e,h) items per thread, all one edge -> 1 ei load,
// float4 ex / seg_sum / alpha; lane-major so already 1 KB per instruction.
__global__ __launch_bounds__(256) void k_norm(
    const int* __restrict__ ei,
    const float* __restrict__ ex_ws,
    const float* __restrict__ seg_sum,
    float* __restrict__ out_alpha,
    const int* __restrict__ flag)
{
    const int base = (blockIdx.x * 256 + threadIdx.x) * 4;  // 5000 blocks exact
    const int h0 = base & 7;                                // 0 or 4
    const int e = base >> 3;

    const int t = get_target(ei, e, *flag);

    const float4v ex = *(const float4v*)(ex_ws + base);
    const float4v den = *(const float4v*)(seg_sum + t * NUM_HEADS + h0);

    float4v a;
#pragma unroll
    for (int j = 0; j < 4; j++) a[j] = ex[j] / (den[j] + 1e-16f);

    *(float4v*)(out_alpha + base) = a;
}

extern "C" void kernel_launch(void* const* d_in, const int* in_sizes, int n_in,
                              void* d_out, int out_size, void* d_ws, size_t ws_size,
                              hipStream_t stream) {
    const int* ei = (const int*)d_in[0];
    const float* msg = (const float*)d_in[1];
    const float* xe = (const float*)d_in[2];
    const float* wt = (const float*)d_in[3];

    float* out_msg = (float*)d_out;                            // (E,128) f32
    float* out_alpha = out_msg + (size_t)NUM_EDGES * DIM;      // (E,8) f32

    char* ws = (char*)d_ws;
    float* ex_ws = (float*)ws;                                 // E*8 f32
    size_t off = (size_t)TOTAL * sizeof(float);
    float* proj = (float*)(ws + off);                          // N*8 f32
    float* seg_sum = (float*)(ws + off + (size_t)NKEYS * 4);   // N*8 f32
    int* flag = (int*)(ws + off + (size_t)NKEYS * 8);

    k_proj<<<NKEYS / 256, 256, 0, stream>>>(xe, wt, (const unsigned*)ei, proj,
                                            seg_sum, flag);
    k_main<<<NUM_EDGES / 32, 256, 0, stream>>>(ei, msg, wt, proj, out_msg,
                                               ex_ws, seg_sum, flag);
    k_norm<<<TOTAL / 1024, 256, 0, stream>>>(ei, ex_ws, seg_sum, out_alpha, flag);
}